// Round 10
// baseline (97.266 us; speedup 1.0000x reference)
//
#include <hip/hip_runtime.h>

// ---------------------------------------------------------------------------
// CMHSAttn v9: fp32 in/out. R9 forensics: harness ws-poison fill (268 MB,
// 40.7 us) is the fixed floor; controllable = attn(~32) + qkv(~7) + comb(~4).
// v9: wave owns FOUR 16-q tiles (64 q) sharing each K/V fragment load; PV
// issued per-tile immediately (pk transient, ~90 VGPR live). SPLIT 4->8 to
// keep 4 waves/SIMD. qkv unchanged (validated R8).
// ---------------------------------------------------------------------------

typedef __attribute__((ext_vector_type(4))) float    f32x4;
typedef __attribute__((ext_vector_type(8))) short    s16x8;
typedef __attribute__((ext_vector_type(4))) short    s16x4;
typedef __attribute__((ext_vector_type(8))) __bf16   bf16x8;
typedef __attribute__((ext_vector_type(4))) unsigned u32x4;

union FragAB { s16x8 s; bf16x8 b; u32x4 u; };

__device__ __forceinline__ short f2bf(float f) {
    unsigned u = __float_as_uint(f);
    u += 0x7fff + ((u >> 16) & 1);          // RNE
    return (short)(u >> 16);
}

#if __has_builtin(__builtin_amdgcn_exp2f)
  #define FASTEXP(x) __builtin_amdgcn_exp2f(x)
  #define QK_SCALE 0.12751744154070513f   // (1/sqrt(128)) * log2(e)
#else
  #define FASTEXP(x) __expf(x)
  #define QK_SCALE 0.08838834764831845f   // 1/sqrt(128)
#endif

// ---------------------------------------------------------------------------
// QKV (unchanged, validated R8): MFMA GEMM; V written PV-slot-permuted:
// v2[h][d][T][c][quad][j] = V[d][ T*64 + c*32 + (j>=4?16:0) + quad*4 + (j&3) ]
// ---------------------------------------------------------------------------
__global__ __launch_bounds__(256) void qkv_kernel(
    const float* __restrict__ x, const float* __restrict__ w,
    short* __restrict__ qT, short* __restrict__ kT, short* __restrict__ v2)
{
    __shared__ __align__(16) short xT[4][16][136];   // [wave][n][c], pad 8
    const int wv   = threadIdx.x >> 6;
    const int lane = threadIdx.x & 63;
    const int colL = lane & 15, quad = lane >> 4;
    const int n0 = blockIdx.x * 64 + wv * 16;
    const int oq = blockIdx.y;                        // 0..3

    #pragma unroll
    for (int rr = 0; rr < 4; ++rr) {
        int c  = rr * 32 + (lane >> 1);
        int nh = (lane & 1) * 8;
        f32x4 a = *(const f32x4*)&x[c * 4096 + n0 + nh];
        f32x4 b = *(const f32x4*)&x[c * 4096 + n0 + nh + 4];
        #pragma unroll
        for (int t = 0; t < 4; ++t) {
            xT[wv][nh + t][c]     = f2bf(a[t]);
            xT[wv][nh + 4 + t][c] = f2bf(b[t]);
        }
    }
    __syncthreads();

    FragAB xb[4];
    #pragma unroll
    for (int ks = 0; ks < 4; ++ks)
        xb[ks].s = *(const s16x8*)&xT[wv][colL][ks * 32 + quad * 8];

    const int T    = blockIdx.x;
    const int wloc = wv * 16 + colL;          // n & 63
    const int cc   = wloc >> 5;
    const int bb   = (wloc >> 4) & 1;
    const int qp   = (wloc >> 2) & 3;
    const int jj   = bb * 4 + (wloc & 3);
    const int vslot = ((T * 2 + cc) * 4 + qp) * 8 + jj;

    #pragma unroll
    for (int i = 0; i < 6; ++i) {
        const int otg  = oq * 6 + i;
        const int ob   = otg * 16;
        const int h    = otg / 3;
        const int kind = otg % 3;             // 0=q, 1=k, 2=v
        f32x4 acc = {0.f, 0.f, 0.f, 0.f};
        #pragma unroll
        for (int ks = 0; ks < 4; ++ks) {
            f32x4 wa0 = *(const f32x4*)&w[(ob + colL) * 128 + ks * 32 + quad * 8];
            f32x4 wa1 = *(const f32x4*)&w[(ob + colL) * 128 + ks * 32 + quad * 8 + 4];
            FragAB wa;
            #pragma unroll
            for (int t = 0; t < 4; ++t) {
                wa.s[t]     = f2bf(wa0[t]);
                wa.s[t + 4] = f2bf(wa1[t]);
            }
            acc = __builtin_amdgcn_mfma_f32_16x16x32_bf16(wa.b, xb[ks].b, acc, 0, 0, 0);
        }
        if (kind == 2) {
            #pragma unroll
            for (int r = 0; r < 4; ++r) {
                int d = quad * 4 + r;
                v2[(h * 16 + d) * 4096 + vslot] = f2bf(acc[r]);
            }
        } else {
            short* dst = (kind == 0) ? qT : kT;
            const float sc = (kind == 0) ? QK_SCALE : 1.0f;
            s16x4 pk;
            #pragma unroll
            for (int r = 0; r < 4; ++r) pk[r] = f2bf(acc[r] * sc);
            *(s16x4*)&dst[(h * 4096 + n0 + colL) * 16 + quad * 4] = pk;
        }
    }
}

// ---------------------------------------------------------------------------
// Attention v9: wave = 64 q rows (four 16-q tiles) x key chunk.
// Block = 4 waves = 256 q; per head 16 blocks; SPLIT=8 -> 1024 blocks.
// Per key tile: 6 shared loads, then per q-tile QK->exp->pack->PV (pk
// transient). Indexing identical to validated R8/R9.
// ---------------------------------------------------------------------------
template<int SPLIT>
__global__ __launch_bounds__(256) void attn_kernel(
    const short* __restrict__ qT, const short* __restrict__ kT,
    const short* __restrict__ v2,
    float* __restrict__ Opart, float* __restrict__ lpart,
    float* __restrict__ out)
{
    const int wv   = threadIdx.x >> 6;
    const int lane = threadIdx.x & 63;
    const int colL = lane & 15, quad = lane >> 4;

    const int bx = blockIdx.x;
    int s, h, b;
    if (SPLIT > 1) { s = bx >> 7; h = (bx >> 4) & 7; b = bx & 15; }
    else           { s = 0;       h = bx >> 4;       b = bx & 15; }
    const int qbase = b * 256 + wv * 64;     // this wave's 64 q rows
    const int nkt = 64 / SPLIT;

    const short* kb  = kT +  h * 4096 * 16;
    const short* vb2 = v2 + (h * 16 + colL) * 4096;

    FragAB qfs[4];                            // B-frags: Q^T[d][q], d<16
    #pragma unroll
    for (int u = 0; u < 4; ++u) {
        qfs[u].s = 0;
        if (quad < 2)
            qfs[u].s = *(const s16x8*)&qT[(h * 4096 + qbase + u * 16 + colL) * 16 + quad * 8];
    }

    f32x4 o[4];
    float l0[4], l1[4];
    #pragma unroll
    for (int u = 0; u < 4; ++u) {
        o[u] = (f32x4){0.f, 0.f, 0.f, 0.f};
        l0[u] = 0.f; l1[u] = 0.f;
    }

    const int kt_base = s * nkt;
    for (int kt = 0; kt < nkt; ++kt) {
        const int T  = kt_base + kt;
        const int m0 = T * 64;

        s16x8 kfr[4];
        #pragma unroll
        for (int t = 0; t < 4; ++t)
            kfr[t] = *(const s16x8*)&kb[(m0 + t * 16 + colL) * 16 + quad * 8];
        s16x8 vfr[2];
        #pragma unroll
        for (int c = 0; c < 2; ++c)
            vfr[c] = *(const s16x8*)&vb2[(T * 2 + c) * 32 + quad * 8];

        #pragma unroll
        for (int u = 0; u < 4; ++u) {
            f32x4 st[4];
            #pragma unroll
            for (int t = 0; t < 4; ++t) {
                FragAB kx; kx.s = kfr[t];
                f32x4 z = {0.f, 0.f, 0.f, 0.f};
                st[t] = __builtin_amdgcn_mfma_f32_16x16x32_bf16(kx.b, qfs[u].b, z, 0, 0, 0);
            }
            unsigned pk[8];
            #pragma unroll
            for (int t = 0; t < 4; ++t) {
                float p0 = FASTEXP(st[t][0]);
                float p1 = FASTEXP(st[t][1]);
                float p2 = FASTEXP(st[t][2]);
                float p3 = FASTEXP(st[t][3]);
                l0[u] += p0 + p2;
                l1[u] += p1 + p3;
                pk[t * 2 + 0] = __builtin_amdgcn_perm(
                    __float_as_uint(p1) + 0x8000u, __float_as_uint(p0) + 0x8000u, 0x07060302u);
                pk[t * 2 + 1] = __builtin_amdgcn_perm(
                    __float_as_uint(p3) + 0x8000u, __float_as_uint(p2) + 0x8000u, 0x07060302u);
            }
            #pragma unroll
            for (int c = 0; c < 2; ++c) {
                FragAB vf, pb;
                vf.s = vfr[c];
                pb.u = (u32x4){pk[4 * c + 0], pk[4 * c + 1], pk[4 * c + 2], pk[4 * c + 3]};
                o[u] = __builtin_amdgcn_mfma_f32_16x16x32_bf16(vf.b, pb.b, o[u], 0, 0, 0);
            }
        }
    }

    #pragma unroll
    for (int u = 0; u < 4; ++u) {
        float l = l0[u] + l1[u];
        l += __shfl_xor(l, 16, 64);
        l += __shfl_xor(l, 32, 64);
        const int q0 = qbase + u * 16;
        if (SPLIT > 1) {
            #pragma unroll
            for (int r = 0; r < 4; ++r)
                Opart[((s * 8 + h) * 16 + quad * 4 + r) * 4096 + q0 + colL] = o[u][r];
            if (quad == 0) lpart[(s * 8 + h) * 4096 + q0 + colL] = l;
        } else {
            const float inv = 1.f / l;
            #pragma unroll
            for (int r = 0; r < 4; ++r)
                out[(h * 16 + quad * 4 + r) * 4096 + q0 + colL] = o[u][r] * inv;
        }
    }
}

// ---------------------------------------------------------------------------
template<int SPLIT>
__global__ __launch_bounds__(256) void combine_kernel(
    const float* __restrict__ Opart, const float* __restrict__ lpart,
    float* __restrict__ out)
{
    const int row = blockIdx.x >> 2;                       // 0..127 = h*16+d
    const int n   = (blockIdx.x & 3) * 1024 + threadIdx.x * 4;
    const int h   = row >> 4;
    f32x4 osum = {0.f, 0.f, 0.f, 0.f}, lsum = {0.f, 0.f, 0.f, 0.f};
    #pragma unroll
    for (int s = 0; s < SPLIT; ++s) {
        osum += *(const f32x4*)&Opart[(s * 128 + row) * 4096 + n];
        lsum += *(const f32x4*)&lpart[(s * 8 + h) * 4096 + n];
    }
    f32x4 res;
    #pragma unroll
    for (int r = 0; r < 4; ++r) res[r] = osum[r] / lsum[r];
    *(f32x4*)&out[row * 4096 + n] = res;
}

// ---------------------------------------------------------------------------
extern "C" void kernel_launch(void* const* d_in, const int* in_sizes, int n_in,
                              void* d_out, int out_size, void* d_ws, size_t ws_size,
                              hipStream_t stream) {
    const float* x = (const float*)d_in[0];   // (128, 4096) fp32
    const float* w = (const float*)d_in[1];   // (384, 128) fp32
    float* out = (float*)d_out;               // (128, 4096) fp32

    char* ws = (char*)d_ws;
    short* qT = (short*)ws;                          // 1 MB
    short* kT = (short*)(ws + (1u << 20));           // 1 MB
    short* vv = (short*)(ws + (2u << 20));           // 1 MB (permuted v2)

    constexpr int SPLIT = 8;
    const size_t opart_bytes = (size_t)SPLIT * 128 * 4096 * 4;   // 16 MB
    const size_t lpart_bytes = (size_t)SPLIT * 8 * 4096 * 4;     // 1 MB
    const size_t need_split  = (3ull << 20) + opart_bytes + lpart_bytes;

    dim3 gq(64, 4);
    qkv_kernel<<<gq, 256, 0, stream>>>(x, w, qT, kT, vv);

    if (ws_size >= need_split) {
        float* Opart = (float*)(ws + (3ull << 20));
        float* lpart = (float*)(ws + (3ull << 20) + opart_bytes);
        attn_kernel<SPLIT><<<SPLIT * 128, 256, 0, stream>>>(qT, kT, vv, Opart, lpart, out);
        combine_kernel<SPLIT><<<512, 256, 0, stream>>>(Opart, lpart, out);
    } else {
        attn_kernel<1><<<128, 256, 0, stream>>>(qT, kT, vv, nullptr, nullptr, out);
    }
}

// Round 11
// 97.125 us; speedup vs baseline: 1.0015x; 1.0015x over previous
//
#include <hip/hip_runtime.h>

// ---------------------------------------------------------------------------
// CMHSAttn v10: fp32 in/out. R9 vs R10 control: per-load compute x2 at equal
// grid/work = neutral -> attn (~32 us) is not load-count-bound. This round
// isolates load LATENCY: R10 kernel + register ping-pong prefetch of next
// key-tile's K/V fragments (occupancy unchanged at 4 waves/SIMD, unlike R7).
// qkv/combine byte-identical to R10.
// ---------------------------------------------------------------------------

typedef __attribute__((ext_vector_type(4))) float    f32x4;
typedef __attribute__((ext_vector_type(8))) short    s16x8;
typedef __attribute__((ext_vector_type(4))) short    s16x4;
typedef __attribute__((ext_vector_type(8))) __bf16   bf16x8;
typedef __attribute__((ext_vector_type(4))) unsigned u32x4;

union FragAB { s16x8 s; bf16x8 b; u32x4 u; };

__device__ __forceinline__ short f2bf(float f) {
    unsigned u = __float_as_uint(f);
    u += 0x7fff + ((u >> 16) & 1);          // RNE
    return (short)(u >> 16);
}

#if __has_builtin(__builtin_amdgcn_exp2f)
  #define FASTEXP(x) __builtin_amdgcn_exp2f(x)
  #define QK_SCALE 0.12751744154070513f   // (1/sqrt(128)) * log2(e)
#else
  #define FASTEXP(x) __expf(x)
  #define QK_SCALE 0.08838834764831845f   // 1/sqrt(128)
#endif

// ---------------------------------------------------------------------------
// QKV (unchanged, validated R8): MFMA GEMM; V written PV-slot-permuted:
// v2[h][d][T][c][quad][j] = V[d][ T*64 + c*32 + (j>=4?16:0) + quad*4 + (j&3) ]
// ---------------------------------------------------------------------------
__global__ __launch_bounds__(256) void qkv_kernel(
    const float* __restrict__ x, const float* __restrict__ w,
    short* __restrict__ qT, short* __restrict__ kT, short* __restrict__ v2)
{
    __shared__ __align__(16) short xT[4][16][136];   // [wave][n][c], pad 8
    const int wv   = threadIdx.x >> 6;
    const int lane = threadIdx.x & 63;
    const int colL = lane & 15, quad = lane >> 4;
    const int n0 = blockIdx.x * 64 + wv * 16;
    const int oq = blockIdx.y;                        // 0..3

    #pragma unroll
    for (int rr = 0; rr < 4; ++rr) {
        int c  = rr * 32 + (lane >> 1);
        int nh = (lane & 1) * 8;
        f32x4 a = *(const f32x4*)&x[c * 4096 + n0 + nh];
        f32x4 b = *(const f32x4*)&x[c * 4096 + n0 + nh + 4];
        #pragma unroll
        for (int t = 0; t < 4; ++t) {
            xT[wv][nh + t][c]     = f2bf(a[t]);
            xT[wv][nh + 4 + t][c] = f2bf(b[t]);
        }
    }
    __syncthreads();

    FragAB xb[4];
    #pragma unroll
    for (int ks = 0; ks < 4; ++ks)
        xb[ks].s = *(const s16x8*)&xT[wv][colL][ks * 32 + quad * 8];

    const int T    = blockIdx.x;
    const int wloc = wv * 16 + colL;          // n & 63
    const int cc   = wloc >> 5;
    const int bb   = (wloc >> 4) & 1;
    const int qp   = (wloc >> 2) & 3;
    const int jj   = bb * 4 + (wloc & 3);
    const int vslot = ((T * 2 + cc) * 4 + qp) * 8 + jj;

    #pragma unroll
    for (int i = 0; i < 6; ++i) {
        const int otg  = oq * 6 + i;
        const int ob   = otg * 16;
        const int h    = otg / 3;
        const int kind = otg % 3;             // 0=q, 1=k, 2=v
        f32x4 acc = {0.f, 0.f, 0.f, 0.f};
        #pragma unroll
        for (int ks = 0; ks < 4; ++ks) {
            f32x4 wa0 = *(const f32x4*)&w[(ob + colL) * 128 + ks * 32 + quad * 8];
            f32x4 wa1 = *(const f32x4*)&w[(ob + colL) * 128 + ks * 32 + quad * 8 + 4];
            FragAB wa;
            #pragma unroll
            for (int t = 0; t < 4; ++t) {
                wa.s[t]     = f2bf(wa0[t]);
                wa.s[t + 4] = f2bf(wa1[t]);
            }
            acc = __builtin_amdgcn_mfma_f32_16x16x32_bf16(wa.b, xb[ks].b, acc, 0, 0, 0);
        }
        if (kind == 2) {
            #pragma unroll
            for (int r = 0; r < 4; ++r) {
                int d = quad * 4 + r;
                v2[(h * 16 + d) * 4096 + vslot] = f2bf(acc[r]);
            }
        } else {
            short* dst = (kind == 0) ? qT : kT;
            const float sc = (kind == 0) ? QK_SCALE : 1.0f;
            s16x4 pk;
            #pragma unroll
            for (int r = 0; r < 4; ++r) pk[r] = f2bf(acc[r] * sc);
            *(s16x4*)&dst[(h * 4096 + n0 + colL) * 16 + quad * 4] = pk;
        }
    }
}

// ---------------------------------------------------------------------------
// Attention v10: wave = 64 q (four 16-q tiles) x key chunk, register
// ping-pong prefetch of K/V fragments. SPLIT=8 -> 1024 blocks.
// ---------------------------------------------------------------------------
template<int SPLIT>
__global__ __launch_bounds__(256) void attn_kernel(
    const short* __restrict__ qT, const short* __restrict__ kT,
    const short* __restrict__ v2,
    float* __restrict__ Opart, float* __restrict__ lpart,
    float* __restrict__ out)
{
    const int wv   = threadIdx.x >> 6;
    const int lane = threadIdx.x & 63;
    const int colL = lane & 15, quad = lane >> 4;

    const int bx = blockIdx.x;
    int s, h, b;
    if (SPLIT > 1) { s = bx >> 7; h = (bx >> 4) & 7; b = bx & 15; }
    else           { s = 0;       h = bx >> 4;       b = bx & 15; }
    const int qbase = b * 256 + wv * 64;     // this wave's 64 q rows
    const int nkt = 64 / SPLIT;              // even

    const short* kb  = kT +  h * 4096 * 16;
    const short* vb2 = v2 + (h * 16 + colL) * 4096;

    FragAB qfs[4];                            // B-frags: Q^T[d][q], d<16
    #pragma unroll
    for (int u = 0; u < 4; ++u) {
        qfs[u].s = 0;
        if (quad < 2)
            qfs[u].s = *(const s16x8*)&qT[(h * 4096 + qbase + u * 16 + colL) * 16 + quad * 8];
    }

    f32x4 o[4];
    float l0[4], l1[4];
    #pragma unroll
    for (int u = 0; u < 4; ++u) {
        o[u] = (f32x4){0.f, 0.f, 0.f, 0.f};
        l0[u] = 0.f; l1[u] = 0.f;
    }

    s16x8 kfA[4], kfB[4], vfA[2], vfB[2];

#define LOAD_TILE(KF, VF, TT)                                                \
    {                                                                        \
        const int T_ = (TT);                                                 \
        const int m0_ = T_ * 64;                                             \
        _Pragma("unroll")                                                    \
        for (int t = 0; t < 4; ++t)                                          \
            KF[t] = *(const s16x8*)&kb[(m0_ + t * 16 + colL) * 16 + quad * 8]; \
        _Pragma("unroll")                                                    \
        for (int c = 0; c < 2; ++c)                                          \
            VF[c] = *(const s16x8*)&vb2[(T_ * 2 + c) * 32 + quad * 8];       \
    }

#define COMPUTE_TILE(KF, VF)                                                 \
    {                                                                        \
        _Pragma("unroll")                                                    \
        for (int u = 0; u < 4; ++u) {                                        \
            f32x4 st[4];                                                     \
            _Pragma("unroll")                                                \
            for (int t = 0; t < 4; ++t) {                                    \
                FragAB kx; kx.s = KF[t];                                     \
                f32x4 z = {0.f, 0.f, 0.f, 0.f};                              \
                st[t] = __builtin_amdgcn_mfma_f32_16x16x32_bf16(kx.b, qfs[u].b, z, 0, 0, 0); \
            }                                                                \
            unsigned pk[8];                                                  \
            _Pragma("unroll")                                                \
            for (int t = 0; t < 4; ++t) {                                    \
                float p0 = FASTEXP(st[t][0]);                                \
                float p1 = FASTEXP(st[t][1]);                                \
                float p2 = FASTEXP(st[t][2]);                                \
                float p3 = FASTEXP(st[t][3]);                                \
                l0[u] += p0 + p2;                                            \
                l1[u] += p1 + p3;                                            \
                pk[t * 2 + 0] = __builtin_amdgcn_perm(                       \
                    __float_as_uint(p1) + 0x8000u, __float_as_uint(p0) + 0x8000u, 0x07060302u); \
                pk[t * 2 + 1] = __builtin_amdgcn_perm(                       \
                    __float_as_uint(p3) + 0x8000u, __float_as_uint(p2) + 0x8000u, 0x07060302u); \
            }                                                                \
            _Pragma("unroll")                                                \
            for (int c = 0; c < 2; ++c) {                                    \
                FragAB vf, pb;                                               \
                vf.s = VF[c];                                                \
                pb.u = (u32x4){pk[4 * c + 0], pk[4 * c + 1], pk[4 * c + 2], pk[4 * c + 3]}; \
                o[u] = __builtin_amdgcn_mfma_f32_16x16x32_bf16(vf.b, pb.b, o[u], 0, 0, 0); \
            }                                                                \
        }                                                                    \
    }

    const int kt_base = s * nkt;
    LOAD_TILE(kfA, vfA, kt_base)
    for (int kt2 = 0; kt2 < nkt; kt2 += 2) {
        LOAD_TILE(kfB, vfB, kt_base + kt2 + 1)       // prefetch odd
        COMPUTE_TILE(kfA, vfA)                       // compute even
        if (kt2 + 2 < nkt)
            LOAD_TILE(kfA, vfA, kt_base + kt2 + 2)   // prefetch even
        COMPUTE_TILE(kfB, vfB)                       // compute odd
    }
#undef LOAD_TILE
#undef COMPUTE_TILE

    #pragma unroll
    for (int u = 0; u < 4; ++u) {
        float l = l0[u] + l1[u];
        l += __shfl_xor(l, 16, 64);
        l += __shfl_xor(l, 32, 64);
        const int q0 = qbase + u * 16;
        if (SPLIT > 1) {
            #pragma unroll
            for (int r = 0; r < 4; ++r)
                Opart[((s * 8 + h) * 16 + quad * 4 + r) * 4096 + q0 + colL] = o[u][r];
            if (quad == 0) lpart[(s * 8 + h) * 4096 + q0 + colL] = l;
        } else {
            const float inv = 1.f / l;
            #pragma unroll
            for (int r = 0; r < 4; ++r)
                out[(h * 16 + quad * 4 + r) * 4096 + q0 + colL] = o[u][r] * inv;
        }
    }
}

// ---------------------------------------------------------------------------
template<int SPLIT>
__global__ __launch_bounds__(256) void combine_kernel(
    const float* __restrict__ Opart, const float* __restrict__ lpart,
    float* __restrict__ out)
{
    const int row = blockIdx.x >> 2;                       // 0..127 = h*16+d
    const int n   = (blockIdx.x & 3) * 1024 + threadIdx.x * 4;
    const int h   = row >> 4;
    f32x4 osum = {0.f, 0.f, 0.f, 0.f}, lsum = {0.f, 0.f, 0.f, 0.f};
    #pragma unroll
    for (int s = 0; s < SPLIT; ++s) {
        osum += *(const f32x4*)&Opart[(s * 128 + row) * 4096 + n];
        lsum += *(const f32x4*)&lpart[(s * 8 + h) * 4096 + n];
    }
    f32x4 res;
    #pragma unroll
    for (int r = 0; r < 4; ++r) res[r] = osum[r] / lsum[r];
    *(f32x4*)&out[row * 4096 + n] = res;
}

// ---------------------------------------------------------------------------
extern "C" void kernel_launch(void* const* d_in, const int* in_sizes, int n_in,
                              void* d_out, int out_size, void* d_ws, size_t ws_size,
                              hipStream_t stream) {
    const float* x = (const float*)d_in[0];   // (128, 4096) fp32
    const float* w = (const float*)d_in[1];   // (384, 128) fp32
    float* out = (float*)d_out;               // (128, 4096) fp32

    char* ws = (char*)d_ws;
    short* qT = (short*)ws;                          // 1 MB
    short* kT = (short*)(ws + (1u << 20));           // 1 MB
    short* vv = (short*)(ws + (2u << 20));           // 1 MB (permuted v2)

    constexpr int SPLIT = 8;
    const size_t opart_bytes = (size_t)SPLIT * 128 * 4096 * 4;   // 16 MB
    const size_t lpart_bytes = (size_t)SPLIT * 8 * 4096 * 4;     // 1 MB
    const size_t need_split  = (3ull << 20) + opart_bytes + lpart_bytes;

    dim3 gq(64, 4);
    qkv_kernel<<<gq, 256, 0, stream>>>(x, w, qT, kT, vv);

    if (ws_size >= need_split) {
        float* Opart = (float*)(ws + (3ull << 20));
        float* lpart = (float*)(ws + (3ull << 20) + opart_bytes);
        attn_kernel<SPLIT><<<SPLIT * 128, 256, 0, stream>>>(qT, kT, vv, Opart, lpart, out);
        combine_kernel<SPLIT><<<512, 256, 0, stream>>>(Opart, lpart, out);
    } else {
        attn_kernel<1><<<128, 256, 0, stream>>>(qT, kT, vv, nullptr, nullptr, out);
    }
}